// Round 1
// baseline (2560.785 us; speedup 1.0000x reference)
//
#include <hip/hip_runtime.h>
#include <hip/hip_bf16.h>

// LPKT+ forward. B=32, S=128, C=256, K=128, DC=128, T=S-1=127 scan steps.
//
// Plan:
//  K0: rs1c[j] = sum_i W1[j][256+i]                     (c_emb is a constant broadcast)
//  K1: per (b,s): AL = [eq|eut]@W1a^T + b1 + correct*rs1c ; pre5 = eq@W5q^T + b5
//  K2: per (b,t): pre23 = [AL[t-1]|it|AL[t]] @ [W2a|W3a]^T + b   ; pre4 = it@W4i^T + b4
//  K3: 32 blocks (one per batch) x 1024 threads; h[256][128] fp32 in LDS (XOR-swizzled),
//      127 sequential steps: matvecs on h_tilde -> LG,z -> MFMA G^T=W4h@h^T -> fused
//      sigmoid update of h -> sparse-qe h_tilde atomics -> y.
// ws usage: 10.44 MB fp32.

typedef __bf16 bf16x8 __attribute__((ext_vector_type(8)));
typedef float f32x4 __attribute__((ext_vector_type(4)));

// swizzled LDS index for h (dword units); XOR bits 2..4 spreads banks for both
// the row-wise b128 fragment reads and the column-tile float4 updates.
#define HIDX(c,k) ((((c)<<7)+(k)) ^ (((c)&7)<<2))

__device__ __forceinline__ float sigmf(float x){
  return __builtin_amdgcn_rcpf(1.0f + __expf(-x));
}

__device__ __forceinline__ bf16x8 cvt8(float4 a, float4 b){
  bf16x8 r;
  r[0]=(__bf16)a.x; r[1]=(__bf16)a.y; r[2]=(__bf16)a.z; r[3]=(__bf16)a.w;
  r[4]=(__bf16)b.x; r[5]=(__bf16)b.y; r[6]=(__bf16)b.z; r[7]=(__bf16)b.w;
  return r;
}

__device__ __forceinline__ f32x4 mfma16(bf16x8 a, bf16x8 b, f32x4 c){
  return __builtin_amdgcn_mfma_f32_16x16x32_bf16(a, b, c, 0, 0, 0);
}

// ---------------- K0: rs1c ----------------
__global__ void k0_rs1c(const float* __restrict__ W1, float* __restrict__ rs1c){
  int j = threadIdx.x;            // 128 threads
  float s = 0.f;
  for (int i = 0; i < 128; i++) s += W1[j*384 + 256 + i];
  rs1c[j] = s;
}

// ---------------- K1: AL + pre5 ----------------
// rows R = b*128+s (4096), 64 rows/block, 64 blocks x 256 threads.
__global__ __launch_bounds__(256) void k1_al(
    const int* __restrict__ qseq, const int* __restrict__ utseq,
    const float* __restrict__ corr,
    const float* __restrict__ Eq, const float* __restrict__ Eut,
    const float* __restrict__ W1, const float* __restrict__ b1,
    const float* __restrict__ W5, const float* __restrict__ b5,
    const float* __restrict__ rs1c,
    float* __restrict__ AL, float* __restrict__ pre5)
{
  __shared__ __bf16 inA[64*256];
  __shared__ float corrs[64];
  __shared__ float b1s[128], b5s[128], rs[128];
  const int tid = threadIdx.x, blk = blockIdx.x;
  if (tid < 128){ b1s[tid]=b1[tid]; b5s[tid]=b5[tid]; rs[tid]=rs1c[tid]; }
  {
    int r = tid >> 2, seg = tid & 3;
    int R = blk*64 + r;
    int qi = qseq[R], ui = utseq[R];
    if (seg == 0) corrs[r] = corr[R];
    for (int i = 0; i < 64; i++){
      int col = seg*64 + i;
      float v = (col < 128) ? Eq[qi*128 + col] : Eut[ui*128 + (col-128)];
      inA[((r*256 + col) ^ ((r&7)<<3))] = (__bf16)v;
    }
  }
  __syncthreads();
  const int w = tid >> 6, lane = tid & 63;
  const int la = lane & 15, g = lane >> 4;
  const int rbase = w*16;
  bf16x8 af[8];
  #pragma unroll
  for (int kt = 0; kt < 8; kt++){
    int idx = ((rbase+la)*256 + kt*32 + g*8) ^ ((la&7)<<3);
    af[kt] = *(const bf16x8*)&inA[idx];
  }
  // group 1: all_learning (W1, K=256)
  for (int jt = 0; jt < 8; jt++){
    f32x4 acc = {0.f,0.f,0.f,0.f};
    const float* Wb = W1 + (jt*16+la)*384;
    #pragma unroll
    for (int kt = 0; kt < 8; kt++){
      const float* p = Wb + kt*32 + g*8;
      acc = mfma16(af[kt], cvt8(*(const float4*)p, *(const float4*)(p+4)), acc);
    }
    int j = jt*16 + la;
    #pragma unroll
    for (int rr = 0; rr < 4; rr++){
      int row = rbase + g*4 + rr;
      int R = blk*64 + row;
      AL[R*128 + j] = acc[rr] + b1s[j] + corrs[row]*rs[j];
    }
  }
  // group 2: pre5 (W5q, K=128 -> eq part only)
  for (int jt = 0; jt < 8; jt++){
    f32x4 acc = {0.f,0.f,0.f,0.f};
    const float* Wb = W5 + (jt*16+la)*256;
    #pragma unroll
    for (int kt = 0; kt < 4; kt++){
      const float* p = Wb + kt*32 + g*8;
      acc = mfma16(af[kt], cvt8(*(const float4*)p, *(const float4*)(p+4)), acc);
    }
    int j = jt*16 + la;
    #pragma unroll
    for (int rr = 0; rr < 4; rr++){
      int row = rbase + g*4 + rr;
      int R = blk*64 + row;
      pre5[R*128 + j] = acc[rr] + b5s[j];
    }
  }
}

// ---------------- K2: pre23 + pre4 ----------------
// rows R = b*127+tau (4064), 64 rows/block, 64 blocks x 256 threads.
__global__ __launch_bounds__(256) void k2_pre(
    const int* __restrict__ itseq, const float* __restrict__ Eit,
    const float* __restrict__ AL,
    const float* __restrict__ W2, const float* __restrict__ W3,
    const float* __restrict__ W4,
    const float* __restrict__ b2, const float* __restrict__ b3,
    const float* __restrict__ b4,
    float* __restrict__ pre23, float* __restrict__ pre4)
{
  __shared__ __bf16 inA[64*384];
  __shared__ int obase[64];
  __shared__ float b2s[128], b3s[128], b4s[128];
  const int tid = threadIdx.x, blk = blockIdx.x;
  if (tid < 128){ b2s[tid]=b2[tid]; b3s[tid]=b3[tid]; b4s[tid]=b4[tid]; }
  {
    int r = tid >> 2, seg = tid & 3;
    int R = blk*64 + r;
    bool valid = (R < 4064);
    int b_ = R / 127, tau = R % 127;
    if (seg == 0) obase[r] = valid ? (b_*127 + tau) : -1;
    int itv = valid ? itseq[b_*128 + tau] : 0;
    for (int i = 0; i < 96; i++){
      int col = seg*96 + i;
      float v = 0.f;
      if (valid){
        if (col < 128)      v = (tau > 0) ? AL[(b_*128 + tau-1)*128 + col] : 0.f;
        else if (col < 256) v = Eit[itv*128 + (col-128)];
        else                v = AL[(b_*128 + tau)*128 + (col-256)];
      }
      inA[((r*384 + col) ^ ((r&7)<<3))] = (__bf16)v;
    }
  }
  __syncthreads();
  const int w = tid >> 6, lane = tid & 63;
  const int la = lane & 15, g = lane >> 4;
  const int rbase = w*16;
  bf16x8 af[12];
  #pragma unroll
  for (int kt = 0; kt < 12; kt++){
    int idx = ((rbase+la)*384 + kt*32 + g*8) ^ ((la&7)<<3);
    af[kt] = *(const bf16x8*)&inA[idx];
  }
  // group 1: m23 pre (W2a|W3a), K=384
  for (int jt = 0; jt < 16; jt++){
    f32x4 acc = {0.f,0.f,0.f,0.f};
    int j = jt*16 + la;
    const float* Wb = (j < 128) ? (W2 + j*512) : (W3 + (j-128)*512);
    #pragma unroll
    for (int kt = 0; kt < 12; kt++){
      const float* p = Wb + kt*32 + g*8;
      acc = mfma16(af[kt], cvt8(*(const float4*)p, *(const float4*)(p+4)), acc);
    }
    float bias = (j < 128) ? b2s[j] : b3s[j-128];
    #pragma unroll
    for (int rr = 0; rr < 4; rr++){
      int row = rbase + g*4 + rr;
      int ob = obase[row];
      if (ob >= 0) pre23[ob*256 + j] = acc[rr] + bias;
    }
  }
  // group 2: pre4 = it@W4i^T + b4 (input cols 128..255 -> af[4..7])
  for (int jt = 0; jt < 8; jt++){
    f32x4 acc = {0.f,0.f,0.f,0.f};
    int j = jt*16 + la;
    const float* Wb = W4 + j*384 + 256;
    #pragma unroll
    for (int kk = 0; kk < 4; kk++){
      const float* p = Wb + kk*32 + g*8;
      acc = mfma16(af[4+kk], cvt8(*(const float4*)p, *(const float4*)(p+4)), acc);
    }
    #pragma unroll
    for (int rr = 0; rr < 4; rr++){
      int row = rbase + g*4 + rr;
      int ob = obase[row];
      if (ob >= 0) pre4[ob*128 + j] = acc[rr] + b4s[j];
    }
  }
}

// ---------------- K3: sequential scan, one block per batch ----------------
// LDS layout (floats): h 32768 | ht0 128 | ht1 128 | m23 256 | LG 128 | z 128
//                      | qe0 256 | qe1 256 | yb 4 | qs(int) 128  => 136720 B
#define K3_LDS_BYTES 136720

__global__ __launch_bounds__(1024) void lpkt_scan(
    const float* __restrict__ qmat, const int* __restrict__ qseq,
    const float* __restrict__ h0,
    const float* __restrict__ W2, const float* __restrict__ W3,
    const float* __restrict__ W4, const float* __restrict__ W5,
    const float* __restrict__ pre23, const float* __restrict__ pre4,
    const float* __restrict__ pre5, float* __restrict__ out)
{
  extern __shared__ float lds[];
  float* h    = lds;
  float* htb0 = lds + 32768;
  float* htb1 = lds + 32896;
  float* m23  = lds + 33024;
  float* LGb  = lds + 33280;
  float* zb   = lds + 33408;
  float* qeb0 = lds + 33536;
  float* qeb1 = lds + 33792;
  float* yb   = lds + 34048;
  int*   qsl  = (int*)(lds + 34052);

  const int tid  = threadIdx.x;
  const int b    = blockIdx.x;
  const int lane = tid & 63;
  const int w    = tid >> 6;
  const int la   = lane & 15, g = lane >> 4;

  // ---- persistent register weights ----
  bf16x8 af[8][4];                      // W4h as MFMA A-fragments (M=j, K=k)
  #pragma unroll
  for (int jt = 0; jt < 8; jt++){
    #pragma unroll
    for (int kt = 0; kt < 4; kt++){
      const float* p = W4 + (jt*16+la)*384 + kt*32 + g*8;
      af[jt][kt] = cvt8(*(const float4*)p, *(const float4*)(p+4));
    }
  }
  const int jA = tid >> 2, kcA = tid & 3;   // m23 matvec: 4 threads/output
  float w23[32];
  {
    const float* p = (jA < 128) ? (W2 + jA*512 + 384 + kcA*32)
                                : (W3 + (jA-128)*512 + 384 + kcA*32);
    #pragma unroll
    for (int i = 0; i < 32; i++) w23[i] = p[i];
  }
  const int jB = tid >> 3, kcB = tid & 7;   // z / y matvecs: 8 threads/output
  float w4l[16], w5h[16];
  {
    const float* p4 = W4 + jB*384 + 128 + kcB*16;
    const float* p5 = W5 + jB*256 + 128 + kcB*16;
    #pragma unroll
    for (int i = 0; i < 16; i++){ w4l[i] = p4[i]; w5h[i] = p5[i]; }
  }

  // ---- init: stage qs, h0, qe0, htilde0 ----
  if (tid < 128) qsl[tid] = qseq[b*128 + tid];
  for (int idx = tid; idx < 8192; idx += 1024){
    int c = idx >> 5, k4 = (idx & 31) << 2;
    float4 v = *(const float4*)(h0 + c*128 + k4);
    *(float4*)&h[HIDX(c, k4)] = v;
  }
  if (tid >= 128 && tid < 256) htb0[tid-128] = 0.f;
  if (tid == 256){ yb[0] = 0.f; out[b*128] = 0.f; }
  __syncthreads();
  if (tid < 256) qeb0[tid] = qmat[qsl[0]*256 + tid];
  __syncthreads();
  {
    int c = tid >> 2, kc = tid & 3;
    float q = qeb0[c];
    if (q != 0.f){
      #pragma unroll
      for (int i = 0; i < 8; i++){
        int k4 = kc*32 + i*4;
        float4 hv = *(const float4*)&h[HIDX(c, k4)];
        atomicAdd(&htb0[k4+0], q*hv.x);
        atomicAdd(&htb0[k4+1], q*hv.y);
        atomicAdd(&htb0[k4+2], q*hv.z);
        atomicAdd(&htb0[k4+3], q*hv.w);
      }
    }
  }
  __syncthreads();

  const float* pre23b = pre23 + b*127*256;
  const float* pre4b  = pre4  + b*127*128;
  const float* pre5b  = pre5  + b*128*128;
  const int c_ = (w << 4) + la;          // this lane's h row in MFMA/update

  for (int tau = 0; tau < 127; tau++){
    float* htc = (tau & 1) ? htb1 : htb0;
    float* htn = (tau & 1) ? htb0 : htb1;
    float* qec = (tau & 1) ? qeb1 : qeb0;
    float* qen = (tau & 1) ? qeb0 : qeb1;

    // ---- phase A: zero htn, prefetch qe[tau+1], m23 matvec ----
    if (tid < 128) htn[tid] = 0.f;
    if (tid >= 256 && tid < 512) qen[tid-256] = qmat[qsl[tau+1]*256 + (tid-256)];
    {
      float s = 0.f;
      #pragma unroll
      for (int i = 0; i < 8; i++){
        float4 v = *(const float4*)&htc[kcA*32 + i*4];
        s += w23[i*4+0]*v.x + w23[i*4+1]*v.y + w23[i*4+2]*v.z + w23[i*4+3]*v.w;
      }
      s += __shfl_xor(s, 1);
      s += __shfl_xor(s, 2);
      if (kcA == 0) m23[jA] = pre23b[tau*256 + jA] + s;
    }
    __syncthreads();                                    // Ba
    if (tid < 128){
      float lp = m23[tid], gp = m23[128 + tid];
      LGb[tid] = sigmf(gp) * sigmf(2.f*lp);             // sig(gl)*(tanh(lg)+1)/2
    }
    __syncthreads();                                    // Bb
    {
      float s = 0.f;
      #pragma unroll
      for (int i = 0; i < 4; i++){
        float4 v = *(const float4*)&LGb[kcB*16 + i*4];
        s += w4l[i*4+0]*v.x + w4l[i*4+1]*v.y + w4l[i*4+2]*v.z + w4l[i*4+3]*v.w;
      }
      s += __shfl_xor(s, 1); s += __shfl_xor(s, 2); s += __shfl_xor(s, 4);
      if (kcB == 0) zb[jB] = pre4b[tau*128 + jB] + s;
    }
    __syncthreads();                                    // B1

    // ---- MFMA G^T = W4h @ h^T, fused sigmoid update of h, h_tilde atomics ----
    {
      bf16x8 bf[4];
      #pragma unroll
      for (int kt = 0; kt < 4; kt++){
        int k0 = kt*32 + g*8;
        float4 x0 = *(const float4*)&h[HIDX(c_, k0)];
        float4 x1 = *(const float4*)&h[HIDX(c_, k0+4)];
        bf[kt] = cvt8(x0, x1);
      }
      float qet = qec[c_], qnv = qen[c_];
      bool nz = (qnv != 0.f);
      #pragma unroll
      for (int jt = 0; jt < 8; jt++){
        f32x4 acc = {0.f,0.f,0.f,0.f};
        #pragma unroll
        for (int kt = 0; kt < 4; kt++)
          acc = mfma16(af[jt][kt], bf[kt], acc);
        int k0 = jt*16 + g*4;           // D row = k-index of h; col = c_ = lane&15
        float4 z4  = *(const float4*)&zb[k0];
        float4 lg4 = *(const float4*)&LGb[k0];
        float4 hp  = *(const float4*)&h[HIDX(c_, k0)];
        float4 hn;
        hn.x = qet*lg4.x + sigmf(acc[0] + z4.x)*hp.x;
        hn.y = qet*lg4.y + sigmf(acc[1] + z4.y)*hp.y;
        hn.z = qet*lg4.z + sigmf(acc[2] + z4.z)*hp.z;
        hn.w = qet*lg4.w + sigmf(acc[3] + z4.w)*hp.w;
        *(float4*)&h[HIDX(c_, k0)] = hn;
        if (nz){
          atomicAdd(&htn[k0+0], qnv*hn.x);
          atomicAdd(&htn[k0+1], qnv*hn.y);
          atomicAdd(&htn[k0+2], qnv*hn.z);
          atomicAdd(&htn[k0+3], qnv*hn.w);
        }
      }
    }
    __syncthreads();                                    // B2

    // ---- y = mean_j sigmoid(pre5 + htilde_new @ W5h^T) ----
    {
      float s = 0.f;
      #pragma unroll
      for (int i = 0; i < 4; i++){
        float4 v = *(const float4*)&htn[kcB*16 + i*4];
        s += w5h[i*4+0]*v.x + w5h[i*4+1]*v.y + w5h[i*4+2]*v.z + w5h[i*4+3]*v.w;
      }
      s += __shfl_xor(s, 1); s += __shfl_xor(s, 2); s += __shfl_xor(s, 4);
      if (kcB == 0){
        float val = sigmf(pre5b[(tau+1)*128 + jB] + s);
        atomicAdd(yb, val);
      }
    }
    __syncthreads();                                    // B3
    if (tid == 0){
      out[b*128 + tau + 1] = yb[0] * (1.f/128.f);
      yb[0] = 0.f;
    }
  }
}

// ---------------- host launch ----------------
extern "C" void kernel_launch(void* const* d_in, const int* in_sizes, int n_in,
                              void* d_out, int out_size, void* d_ws, size_t ws_size,
                              hipStream_t stream) {
  const int*   qseq  = (const int*)  d_in[0];
  const int*   itseq = (const int*)  d_in[1];
  const int*   utseq = (const int*)  d_in[2];
  const float* corr  = (const float*)d_in[3];
  const float* Eq    = (const float*)d_in[4];
  const float* Eit   = (const float*)d_in[5];
  const float* Eut   = (const float*)d_in[6];
  const float* qmat  = (const float*)d_in[7];
  const float* h0    = (const float*)d_in[8];
  const float* W1    = (const float*)d_in[9];
  const float* b1    = (const float*)d_in[10];
  const float* W2    = (const float*)d_in[11];
  const float* b2    = (const float*)d_in[12];
  const float* W3    = (const float*)d_in[13];
  const float* b3    = (const float*)d_in[14];
  const float* W4    = (const float*)d_in[15];
  const float* b4    = (const float*)d_in[16];
  const float* W5    = (const float*)d_in[17];
  const float* b5    = (const float*)d_in[18];
  float* out = (float*)d_out;

  float* ws    = (float*)d_ws;          // needs ~10.5 MB
  float* AL    = ws;                    // 4096*128
  float* pre5  = ws + 524288;           // 4096*128
  float* pre23 = ws + 1048576;          // 4064*256
  float* pre4  = ws + 2088960;          // 4064*128
  float* rs1c  = ws + 2609152;          // 128

  (void)hipFuncSetAttribute(reinterpret_cast<const void*>(&lpkt_scan),
                            hipFuncAttributeMaxDynamicSharedMemorySize,
                            K3_LDS_BYTES);

  hipLaunchKernelGGL(k0_rs1c, dim3(1), dim3(128), 0, stream, W1, rs1c);
  hipLaunchKernelGGL(k1_al, dim3(64), dim3(256), 0, stream,
                     qseq, utseq, corr, Eq, Eut, W1, b1, W5, b5, rs1c, AL, pre5);
  hipLaunchKernelGGL(k2_pre, dim3(64), dim3(256), 0, stream,
                     itseq, Eit, AL, W2, W3, W4, b2, b3, b4, pre23, pre4);
  hipLaunchKernelGGL(lpkt_scan, dim3(32), dim3(1024), K3_LDS_BYTES, stream,
                     qmat, qseq, h0, W2, W3, W4, W5, pre23, pre4, pre5, out);
}

// Round 2
// 1242.543 us; speedup vs baseline: 2.0609x; 2.0609x over previous
//
#include <hip/hip_runtime.h>
#include <hip/hip_bf16.h>

// LPKT+ forward. B=32, S=128, C=256, K=128, DC=128, T=127 scan steps.
//
//  K0: rs1c[j] = sum_i W1[j][256+i]
//  K1: AL = [eq|eut]@W1a^T + b1 + correct*rs1c ; pre5 = eq@W5q^T + b5
//  K2: pre23 = [AL[t-1]|it|AL[t]] @ [W2a|W3a]^T + b ; pre4 = it@W4i^T + b4
//  K3 (scan): 32 blocks x 512 threads, h[256][128] fp32 in LDS (swizzled).
//      Per step: m23 matvec via per-wave MFMA (x broadcast, hi/lo bf16) ->
//      LG in-register -> z matvec MFMA -> G^T = W4h@h^T MFMA + fused sigmoid
//      update -> sparse qe atomics for h_tilde -> stream h_tilde to ws.
//      3 barriers/step; qe/pre23/pre4 prefetched under the main phase.
//  K4: batched y = mean_j sigmoid(pre5 + W5h @ ht_hist) for all (b,s).

typedef __bf16 bf16x8 __attribute__((ext_vector_type(8)));
typedef float f32x4 __attribute__((ext_vector_type(4)));

#define HIDX(c,k) ((((c)<<7)+(k)) ^ (((c)&7)<<2))

__device__ __forceinline__ float sigmf(float x){
  return __builtin_amdgcn_rcpf(1.0f + __expf(-x));
}

__device__ __forceinline__ bf16x8 cvt8(float4 a, float4 b){
  bf16x8 r;
  r[0]=(__bf16)a.x; r[1]=(__bf16)a.y; r[2]=(__bf16)a.z; r[3]=(__bf16)a.w;
  r[4]=(__bf16)b.x; r[5]=(__bf16)b.y; r[6]=(__bf16)b.z; r[7]=(__bf16)b.w;
  return r;
}

// hi/lo bf16 split of 8 fp32 values (fp32-grade MFMA input)
__device__ __forceinline__ void mk_hilo(float4 a, float4 b, bf16x8& hi, bf16x8& lo){
  float v[8] = {a.x,a.y,a.z,a.w,b.x,b.y,b.z,b.w};
  #pragma unroll
  for (int i = 0; i < 8; i++){
    __bf16 h = (__bf16)v[i];
    hi[i] = h;
    lo[i] = (__bf16)(v[i] - (float)h);
  }
}

__device__ __forceinline__ f32x4 mfma16(bf16x8 a, bf16x8 b, f32x4 c){
  return __builtin_amdgcn_mfma_f32_16x16x32_bf16(a, b, c, 0, 0, 0);
}

// ---------------- K0 ----------------
__global__ void k0_rs1c(const float* __restrict__ W1, float* __restrict__ rs1c){
  int j = threadIdx.x;
  float s = 0.f;
  for (int i = 0; i < 128; i++) s += W1[j*384 + 256 + i];
  rs1c[j] = s;
}

// ---------------- K1 ----------------
__global__ __launch_bounds__(256) void k1_al(
    const int* __restrict__ qseq, const int* __restrict__ utseq,
    const float* __restrict__ corr,
    const float* __restrict__ Eq, const float* __restrict__ Eut,
    const float* __restrict__ W1, const float* __restrict__ b1,
    const float* __restrict__ W5, const float* __restrict__ b5,
    const float* __restrict__ rs1c,
    float* __restrict__ AL, float* __restrict__ pre5)
{
  __shared__ __bf16 inA[64*256];
  __shared__ float corrs[64];
  __shared__ float b1s[128], b5s[128], rs[128];
  const int tid = threadIdx.x, blk = blockIdx.x;
  if (tid < 128){ b1s[tid]=b1[tid]; b5s[tid]=b5[tid]; rs[tid]=rs1c[tid]; }
  {
    int r = tid >> 2, seg = tid & 3;
    int R = blk*64 + r;
    int qi = qseq[R], ui = utseq[R];
    if (seg == 0) corrs[r] = corr[R];
    for (int i = 0; i < 64; i++){
      int col = seg*64 + i;
      float v = (col < 128) ? Eq[qi*128 + col] : Eut[ui*128 + (col-128)];
      inA[((r*256 + col) ^ ((r&7)<<3))] = (__bf16)v;
    }
  }
  __syncthreads();
  const int w = tid >> 6, lane = tid & 63;
  const int la = lane & 15, g = lane >> 4;
  const int rbase = w*16;
  bf16x8 af[8];
  #pragma unroll
  for (int kt = 0; kt < 8; kt++){
    int idx = ((rbase+la)*256 + kt*32 + g*8) ^ ((la&7)<<3);
    af[kt] = *(const bf16x8*)&inA[idx];
  }
  for (int jt = 0; jt < 8; jt++){
    f32x4 acc = {0.f,0.f,0.f,0.f};
    const float* Wb = W1 + (jt*16+la)*384;
    #pragma unroll
    for (int kt = 0; kt < 8; kt++){
      const float* p = Wb + kt*32 + g*8;
      acc = mfma16(af[kt], cvt8(*(const float4*)p, *(const float4*)(p+4)), acc);
    }
    int j = jt*16 + la;
    #pragma unroll
    for (int rr = 0; rr < 4; rr++){
      int row = rbase + g*4 + rr;
      int R = blk*64 + row;
      AL[R*128 + j] = acc[rr] + b1s[j] + corrs[row]*rs[j];
    }
  }
  for (int jt = 0; jt < 8; jt++){
    f32x4 acc = {0.f,0.f,0.f,0.f};
    const float* Wb = W5 + (jt*16+la)*256;
    #pragma unroll
    for (int kt = 0; kt < 4; kt++){
      const float* p = Wb + kt*32 + g*8;
      acc = mfma16(af[kt], cvt8(*(const float4*)p, *(const float4*)(p+4)), acc);
    }
    int j = jt*16 + la;
    #pragma unroll
    for (int rr = 0; rr < 4; rr++){
      int row = rbase + g*4 + rr;
      int R = blk*64 + row;
      pre5[R*128 + j] = acc[rr] + b5s[j];
    }
  }
}

// ---------------- K2 ----------------
__global__ __launch_bounds__(256) void k2_pre(
    const int* __restrict__ itseq, const float* __restrict__ Eit,
    const float* __restrict__ AL,
    const float* __restrict__ W2, const float* __restrict__ W3,
    const float* __restrict__ W4,
    const float* __restrict__ b2, const float* __restrict__ b3,
    const float* __restrict__ b4,
    float* __restrict__ pre23, float* __restrict__ pre4)
{
  __shared__ __bf16 inA[64*384];
  __shared__ int obase[64];
  __shared__ float b2s[128], b3s[128], b4s[128];
  const int tid = threadIdx.x, blk = blockIdx.x;
  if (tid < 128){ b2s[tid]=b2[tid]; b3s[tid]=b3[tid]; b4s[tid]=b4[tid]; }
  {
    int r = tid >> 2, seg = tid & 3;
    int R = blk*64 + r;
    bool valid = (R < 4064);
    int b_ = R / 127, tau = R % 127;
    if (seg == 0) obase[r] = valid ? (b_*127 + tau) : -1;
    int itv = valid ? itseq[b_*128 + tau] : 0;
    for (int i = 0; i < 96; i++){
      int col = seg*96 + i;
      float v = 0.f;
      if (valid){
        if (col < 128)      v = (tau > 0) ? AL[(b_*128 + tau-1)*128 + col] : 0.f;
        else if (col < 256) v = Eit[itv*128 + (col-128)];
        else                v = AL[(b_*128 + tau)*128 + (col-256)];
      }
      inA[((r*384 + col) ^ ((r&7)<<3))] = (__bf16)v;
    }
  }
  __syncthreads();
  const int w = tid >> 6, lane = tid & 63;
  const int la = lane & 15, g = lane >> 4;
  const int rbase = w*16;
  bf16x8 af[12];
  #pragma unroll
  for (int kt = 0; kt < 12; kt++){
    int idx = ((rbase+la)*384 + kt*32 + g*8) ^ ((la&7)<<3);
    af[kt] = *(const bf16x8*)&inA[idx];
  }
  for (int jt = 0; jt < 16; jt++){
    f32x4 acc = {0.f,0.f,0.f,0.f};
    int j = jt*16 + la;
    const float* Wb = (j < 128) ? (W2 + j*512) : (W3 + (j-128)*512);
    #pragma unroll
    for (int kt = 0; kt < 12; kt++){
      const float* p = Wb + kt*32 + g*8;
      acc = mfma16(af[kt], cvt8(*(const float4*)p, *(const float4*)(p+4)), acc);
    }
    float bias = (j < 128) ? b2s[j] : b3s[j-128];
    #pragma unroll
    for (int rr = 0; rr < 4; rr++){
      int row = rbase + g*4 + rr;
      int ob = obase[row];
      if (ob >= 0) pre23[ob*256 + j] = acc[rr] + bias;
    }
  }
  for (int jt = 0; jt < 8; jt++){
    f32x4 acc = {0.f,0.f,0.f,0.f};
    int j = jt*16 + la;
    const float* Wb = W4 + j*384 + 256;
    #pragma unroll
    for (int kk = 0; kk < 4; kk++){
      const float* p = Wb + kk*32 + g*8;
      acc = mfma16(af[4+kk], cvt8(*(const float4*)p, *(const float4*)(p+4)), acc);
    }
    #pragma unroll
    for (int rr = 0; rr < 4; rr++){
      int row = rbase + g*4 + rr;
      int ob = obase[row];
      if (ob >= 0) pre4[ob*128 + j] = acc[rr] + b4s[j];
    }
  }
}

// ---------------- K3: scan, 32 blocks x 512 threads ----------------
// LDS floats: h 32768 | htb0 128 | htb1 128 | LGb 128 | zb 128 |
//             qeb0 256 | qeb1 256 | p23L 512 | p4L 256 | qsl(int) 128
#define SCAN_LDS_FLOATS (32768+128+128+128+128+256+256+512+256+128)
#define SCAN_LDS_BYTES  (SCAN_LDS_FLOATS*4)

__global__ __launch_bounds__(512, 2) void lpkt_scan(
    const float* __restrict__ qmat, const int* __restrict__ qseq,
    const float* __restrict__ h0,
    const float* __restrict__ W2, const float* __restrict__ W3,
    const float* __restrict__ W4,
    const float* __restrict__ pre23, const float* __restrict__ pre4,
    float* __restrict__ hist)
{
  extern __shared__ float lds[];
  float* h    = lds;
  float* htb0 = lds + 32768;
  float* htb1 = lds + 32896;
  float* LGb  = lds + 33024;
  float* zb   = lds + 33152;
  float* qeb0 = lds + 33280;
  float* qeb1 = lds + 33536;
  float* p23L = lds + 33792;      // [2][256]
  float* p4L  = lds + 34304;      // [2][128]
  int*   qsl  = (int*)(lds + 34560);

  const int tid  = threadIdx.x;
  const int b    = blockIdx.x;
  const int lane = tid & 63;
  const int w    = tid >> 6;           // 8 waves
  const int la   = lane & 15, g = lane >> 4;

  // ---- persistent register weight fragments ----
  bf16x8 af[8][4];                     // W4h (full, replicated per wave)
  #pragma unroll
  for (int jt = 0; jt < 8; jt++){
    #pragma unroll
    for (int kt = 0; kt < 4; kt++){
      const float* p = W4 + (jt*16+la)*384 + kt*32 + g*8;
      af[jt][kt] = cvt8(*(const float4*)p, *(const float4*)(p+4));
    }
  }
  bf16x8 af23[2][4];                   // W2h tile w, W3h tile w
  bf16x8 af4l[4];                      // W4l tile w
  #pragma unroll
  for (int kt = 0; kt < 4; kt++){
    const float* p2 = W2 + (w*16+la)*512 + 384 + kt*32 + g*8;
    const float* p3 = W3 + (w*16+la)*512 + 384 + kt*32 + g*8;
    const float* p4 = W4 + (w*16+la)*384 + 128 + kt*32 + g*8;
    af23[0][kt] = cvt8(*(const float4*)p2, *(const float4*)(p2+4));
    af23[1][kt] = cvt8(*(const float4*)p3, *(const float4*)(p3+4));
    af4l[kt]    = cvt8(*(const float4*)p4, *(const float4*)(p4+4));
  }

  // ---- init staging ----
  if (tid < 128) qsl[tid] = qseq[b*128 + tid];
  __syncthreads();
  for (int idx = tid; idx < 8192; idx += 512){
    int c = idx >> 5, k4 = (idx & 31) << 2;
    *(float4*)&h[HIDX(c, k4)] = *(const float4*)(h0 + c*128 + k4);
  }
  const float* pre23b = pre23 + b*127*256;
  const float* pre4b  = pre4  + b*127*128;
  if (tid < 64)       *(float4*)&qeb0[tid*4] = *(const float4*)(qmat + (size_t)qsl[0]*256 + tid*4);
  else if (tid < 128) *(float4*)&qeb1[(tid-64)*4] = *(const float4*)(qmat + (size_t)qsl[1]*256 + (tid-64)*4);
  else if (tid < 192) *(float4*)&p23L[(tid-128)*4] = *(const float4*)(pre23b + (tid-128)*4);
  else if (tid < 224) *(float4*)&p4L[(tid-192)*4]  = *(const float4*)(pre4b  + (tid-192)*4);
  else if (tid < 256){ float4 z4 = {0.f,0.f,0.f,0.f}; *(float4*)&htb0[(tid-224)*4] = z4; }
  __syncthreads();
  if (tid < 256){
    float q = qeb0[tid];
    if (q != 0.f){
      #pragma unroll
      for (int i = 0; i < 8; i++){
        int k4 = ((tid & 3)*8 + i)*4;       // spread start to cut contention
        k4 &= 127;
        float4 hv = *(const float4*)&h[HIDX(tid, k4)];
        atomicAdd(&htb0[k4+0], q*hv.x);
        atomicAdd(&htb0[k4+1], q*hv.y);
        atomicAdd(&htb0[k4+2], q*hv.z);
        atomicAdd(&htb0[k4+3], q*hv.w);
      }
    }
  }
  __syncthreads();

  const int c_0 = w*32 + la, c_1 = c_0 + 16;

  for (int tau = 0; tau < 127; tau++){
    float* htc = (tau & 1) ? htb1 : htb0;
    float* htn = (tau & 1) ? htb0 : htb1;
    float* qec = (tau & 1) ? qeb1 : qeb0;
    float* qen = (tau & 1) ? qeb0 : qeb1;
    const float* p23c = p23L + (tau & 1)*256;
    const float* p4c  = p4L  + (tau & 1)*128;

    // ---- P0: scalars, zero htn, m23 via MFMA, LG in-register ----
    const float qet[2] = {qec[c_0], qec[c_1]};
    const float qnv[2] = {qen[c_0], qen[c_1]};
    if (tid < 128) htn[tid] = 0.f;
    {
      bf16x8 xh[4], xl[4];
      #pragma unroll
      for (int kt = 0; kt < 4; kt++){
        int k0 = kt*32 + g*8;
        mk_hilo(*(const float4*)&htc[k0], *(const float4*)&htc[k0+4], xh[kt], xl[kt]);
      }
      f32x4 aL = {0.f,0.f,0.f,0.f}, aG = {0.f,0.f,0.f,0.f};
      #pragma unroll
      for (int kt = 0; kt < 4; kt++){
        aL = mfma16(af23[0][kt], xh[kt], aL);
        aL = mfma16(af23[0][kt], xl[kt], aL);
        aG = mfma16(af23[1][kt], xh[kt], aG);
        aG = mfma16(af23[1][kt], xl[kt], aG);
      }
      float4 lp4 = *(const float4*)&p23c[w*16 + g*4];
      float4 gp4 = *(const float4*)&p23c[128 + w*16 + g*4];
      if (la == 0){
        float4 LG4;
        LG4.x = sigmf(aG[0]+gp4.x) * sigmf(2.f*(aL[0]+lp4.x));
        LG4.y = sigmf(aG[1]+gp4.y) * sigmf(2.f*(aL[1]+lp4.y));
        LG4.z = sigmf(aG[2]+gp4.z) * sigmf(2.f*(aL[2]+lp4.z));
        LG4.w = sigmf(aG[3]+gp4.w) * sigmf(2.f*(aL[3]+lp4.w));
        *(float4*)&LGb[w*16 + g*4] = LG4;
      }
    }
    __syncthreads();                                    // Bb

    // ---- z = W4l @ LG + pre4 (per-wave MFMA) ----
    {
      bf16x8 lh[4], ll[4];
      #pragma unroll
      for (int kt = 0; kt < 4; kt++){
        int k0 = kt*32 + g*8;
        mk_hilo(*(const float4*)&LGb[k0], *(const float4*)&LGb[k0+4], lh[kt], ll[kt]);
      }
      f32x4 az = {0.f,0.f,0.f,0.f};
      #pragma unroll
      for (int kt = 0; kt < 4; kt++){
        az = mfma16(af4l[kt], lh[kt], az);
        az = mfma16(af4l[kt], ll[kt], az);
      }
      if (la == 0){
        float4 zp = *(const float4*)&p4c[w*16 + g*4];
        float4 z4 = {az[0]+zp.x, az[1]+zp.y, az[2]+zp.z, az[3]+zp.w};
        *(float4*)&zb[w*16 + g*4] = z4;
      }
    }
    __syncthreads();                                    // B1

    // ---- main: prefetch issue, G^T MFMA + fused update + h_tilde ----
    float4 pf23, pf4, pfqe;
    const bool do23 = (tau+1 < 127) && (tid < 64);
    const bool do4  = (tau+1 < 127) && (tid >= 64) && (tid < 96);
    const bool doqe = (tau+2 < 128) && (tid >= 448);
    if (do23) pf23 = *(const float4*)(pre23b + (tau+1)*256 + tid*4);
    if (do4)  pf4  = *(const float4*)(pre4b  + (tau+1)*128 + (tid-64)*4);
    if (doqe) pfqe = *(const float4*)(qmat + (size_t)qsl[tau+2]*256 + (tid-448)*4);

    const int cc[2] = {c_0, c_1};
    #pragma unroll
    for (int cg = 0; cg < 2; cg++){
      const int c_ = cc[cg];
      bf16x8 bfv[4];
      #pragma unroll
      for (int kt = 0; kt < 4; kt++){
        int k0 = kt*32 + g*8;
        bfv[kt] = cvt8(*(const float4*)&h[HIDX(c_, k0)],
                       *(const float4*)&h[HIDX(c_, k0+4)]);
      }
      const float qe_t = qet[cg], qe_n = qnv[cg];
      const bool nz = (qe_n != 0.f);
      #pragma unroll
      for (int jt = 0; jt < 8; jt++){
        f32x4 acc = {0.f,0.f,0.f,0.f};
        #pragma unroll
        for (int kt = 0; kt < 4; kt++)
          acc = mfma16(af[jt][kt], bfv[kt], acc);
        int k0 = jt*16 + g*4;
        float4 z4  = *(const float4*)&zb[k0];
        float4 lg4 = *(const float4*)&LGb[k0];
        float4 hp  = *(const float4*)&h[HIDX(c_, k0)];
        float4 hn;
        hn.x = qe_t*lg4.x + sigmf(acc[0] + z4.x)*hp.x;
        hn.y = qe_t*lg4.y + sigmf(acc[1] + z4.y)*hp.y;
        hn.z = qe_t*lg4.z + sigmf(acc[2] + z4.z)*hp.z;
        hn.w = qe_t*lg4.w + sigmf(acc[3] + z4.w)*hp.w;
        *(float4*)&h[HIDX(c_, k0)] = hn;
        if (nz){
          atomicAdd(&htn[k0+0], qe_n*hn.x);
          atomicAdd(&htn[k0+1], qe_n*hn.y);
          atomicAdd(&htn[k0+2], qe_n*hn.z);
          atomicAdd(&htn[k0+3], qe_n*hn.w);
        }
      }
    }
    // prefetch writes (consumed only after B2 of this step)
    if (do23) *(float4*)&p23L[((tau+1)&1)*256 + tid*4] = pf23;
    if (do4)  *(float4*)&p4L[((tau+1)&1)*128 + (tid-64)*4] = pf4;
    if (doqe) *(float4*)&qec[(tid-448)*4] = pfqe;       // qe[tau+2] -> current qec buffer
    __syncthreads();                                    // B2

    // stream h_tilde[tau+1] to workspace (off critical path)
    if (tid < 32){
      float4 v = *(const float4*)&htn[tid*4];
      *(float4*)(hist + ((size_t)b*127 + tau)*128 + tid*4) = v;
    }
  }
}

// ---------------- K4: batched y ----------------
__global__ __launch_bounds__(128) void k4_y(
    const float* __restrict__ hist, const float* __restrict__ pre5,
    const float* __restrict__ W5, float* __restrict__ out)
{
  const int R = blockIdx.x;            // 0..4095 = b*128+s
  const int s = R & 127, b = R >> 7;
  const int j = threadIdx.x;
  __shared__ float xs[128];
  __shared__ float partial[2];
  if (s == 0){ if (j == 0) out[R] = 0.f; return; }
  xs[j] = hist[((size_t)b*127 + (s-1))*128 + j];
  __syncthreads();
  const float* wr = W5 + j*256 + 128;
  float acc = pre5[(size_t)R*128 + j];
  #pragma unroll
  for (int k = 0; k < 128; k += 4){
    float4 wv = *(const float4*)&wr[k];
    float4 xv = *(const float4*)&xs[k];
    acc += wv.x*xv.x + wv.y*xv.y + wv.z*xv.z + wv.w*xv.w;
  }
  float v = sigmf(acc);
  #pragma unroll
  for (int m = 1; m < 64; m <<= 1) v += __shfl_xor(v, m);
  if ((j & 63) == 0) partial[j >> 6] = v;
  __syncthreads();
  if (j == 0) out[R] = (partial[0] + partial[1]) * (1.f/128.f);
}

// ---------------- host launch ----------------
extern "C" void kernel_launch(void* const* d_in, const int* in_sizes, int n_in,
                              void* d_out, int out_size, void* d_ws, size_t ws_size,
                              hipStream_t stream) {
  const int*   qseq  = (const int*)  d_in[0];
  const int*   itseq = (const int*)  d_in[1];
  const int*   utseq = (const int*)  d_in[2];
  const float* corr  = (const float*)d_in[3];
  const float* Eq    = (const float*)d_in[4];
  const float* Eit   = (const float*)d_in[5];
  const float* Eut   = (const float*)d_in[6];
  const float* qmat  = (const float*)d_in[7];
  const float* h0    = (const float*)d_in[8];
  const float* W1    = (const float*)d_in[9];
  const float* b1    = (const float*)d_in[10];
  const float* W2    = (const float*)d_in[11];
  const float* b2    = (const float*)d_in[12];
  const float* W3    = (const float*)d_in[13];
  const float* b3    = (const float*)d_in[14];
  const float* W4    = (const float*)d_in[15];
  const float* b4    = (const float*)d_in[16];
  const float* W5    = (const float*)d_in[17];
  const float* b5    = (const float*)d_in[18];
  float* out = (float*)d_out;

  float* ws    = (float*)d_ws;
  float* AL    = ws;                    // 4096*128 ; reused as hist after k2
  float* hist  = ws;                    // 32*127*128 <= AL size
  float* pre5  = ws + 524288;           // 4096*128
  float* pre23 = ws + 1048576;          // 4064*256
  float* pre4  = ws + 2088960;          // 4064*128
  float* rs1c  = ws + 2609152;          // 128

  (void)hipFuncSetAttribute(reinterpret_cast<const void*>(&lpkt_scan),
                            hipFuncAttributeMaxDynamicSharedMemorySize,
                            SCAN_LDS_BYTES);

  hipLaunchKernelGGL(k0_rs1c, dim3(1), dim3(128), 0, stream, W1, rs1c);
  hipLaunchKernelGGL(k1_al, dim3(64), dim3(256), 0, stream,
                     qseq, utseq, corr, Eq, Eut, W1, b1, W5, b5, rs1c, AL, pre5);
  hipLaunchKernelGGL(k2_pre, dim3(64), dim3(256), 0, stream,
                     itseq, Eit, AL, W2, W3, W4, b2, b3, b4, pre23, pre4);
  hipLaunchKernelGGL(lpkt_scan, dim3(32), dim3(512), SCAN_LDS_BYTES, stream,
                     qmat, qseq, h0, W2, W3, W4, pre23, pre4, hist);
  hipLaunchKernelGGL(k4_y, dim3(4096), dim3(128), 0, stream,
                     hist, pre5, W5, out);
}

// Round 3
// 1062.459 us; speedup vs baseline: 2.4102x; 1.1695x over previous
//
#include <hip/hip_runtime.h>
#include <hip/hip_bf16.h>

// LPKT+ forward. B=32, S=128, C=256, K=128, DC=128, T=127 scan steps.
//
//  K0: rs1c[j] = sum_i W1[j][256+i]
//  K1: AL = [eq|eut]@W1a^T + b1 + correct*rs1c ; pre5 = eq@W5q^T + b5
//  K2: pre23 = [AL[t-1]|it|AL[t]] @ [W2a|W3a]^T + b ; pre4 = it@W4i^T + b4
//  K3 (scan): 32 blocks x 512 threads (8 waves).
//      h state lives in REGISTERS (fp32, D-fragment layout, 64 VGPR/thread) +
//      a bf16 shadow of h in LDS (double-buffered, swizzled) as MFMA B-operand.
//      Wave pairs split the k-dimension (W4h fragments 64 regs/wave); each
//      pair owns 64 columns. 3 barriers/step; qe/pre23/pre4 prefetched.
//  K4: batched y = mean_j sigmoid(pre5 + W5h @ ht_hist) for all (b,s).

typedef __bf16 bf16x8 __attribute__((ext_vector_type(8)));
typedef __bf16 bf16x4 __attribute__((ext_vector_type(4)));
typedef float f32x4 __attribute__((ext_vector_type(4)));

// bf16 shadow-h element index (within one 256x128 buffer); XOR swizzle keeps
// b128 reads (k=kt*32+g*8) and b64 writes (k=jt*16+g*4) bank-uniform.
#define HBIDX(c,k) ((((c)<<7)) + ((k) ^ (((c)&15)<<3)))

__device__ __forceinline__ float sigmf(float x){
  return __builtin_amdgcn_rcpf(1.0f + __expf(-x));
}

__device__ __forceinline__ bf16x8 cvt8(float4 a, float4 b){
  bf16x8 r;
  r[0]=(__bf16)a.x; r[1]=(__bf16)a.y; r[2]=(__bf16)a.z; r[3]=(__bf16)a.w;
  r[4]=(__bf16)b.x; r[5]=(__bf16)b.y; r[6]=(__bf16)b.z; r[7]=(__bf16)b.w;
  return r;
}

// hi/lo bf16 split of 8 fp32 values (fp32-grade MFMA input)
__device__ __forceinline__ void mk_hilo(float4 a, float4 b, bf16x8& hi, bf16x8& lo){
  float v[8] = {a.x,a.y,a.z,a.w,b.x,b.y,b.z,b.w};
  #pragma unroll
  for (int i = 0; i < 8; i++){
    __bf16 h = (__bf16)v[i];
    hi[i] = h;
    lo[i] = (__bf16)(v[i] - (float)h);
  }
}

__device__ __forceinline__ f32x4 mfma16(bf16x8 a, bf16x8 b, f32x4 c){
  return __builtin_amdgcn_mfma_f32_16x16x32_bf16(a, b, c, 0, 0, 0);
}

// ---------------- K0 ----------------
__global__ void k0_rs1c(const float* __restrict__ W1, float* __restrict__ rs1c){
  int j = threadIdx.x;
  float s = 0.f;
  for (int i = 0; i < 128; i++) s += W1[j*384 + 256 + i];
  rs1c[j] = s;
}

// ---------------- K1 ----------------
__global__ __launch_bounds__(256) void k1_al(
    const int* __restrict__ qseq, const int* __restrict__ utseq,
    const float* __restrict__ corr,
    const float* __restrict__ Eq, const float* __restrict__ Eut,
    const float* __restrict__ W1, const float* __restrict__ b1,
    const float* __restrict__ W5, const float* __restrict__ b5,
    const float* __restrict__ rs1c,
    float* __restrict__ AL, float* __restrict__ pre5)
{
  __shared__ __bf16 inA[64*256];
  __shared__ float corrs[64];
  __shared__ float b1s[128], b5s[128], rs[128];
  const int tid = threadIdx.x, blk = blockIdx.x;
  if (tid < 128){ b1s[tid]=b1[tid]; b5s[tid]=b5[tid]; rs[tid]=rs1c[tid]; }
  {
    int r = tid >> 2, seg = tid & 3;
    int R = blk*64 + r;
    int qi = qseq[R], ui = utseq[R];
    if (seg == 0) corrs[r] = corr[R];
    for (int i = 0; i < 64; i++){
      int col = seg*64 + i;
      float v = (col < 128) ? Eq[qi*128 + col] : Eut[ui*128 + (col-128)];
      inA[((r*256 + col) ^ ((r&7)<<3))] = (__bf16)v;
    }
  }
  __syncthreads();
  const int w = tid >> 6, lane = tid & 63;
  const int la = lane & 15, g = lane >> 4;
  const int rbase = w*16;
  bf16x8 af[8];
  #pragma unroll
  for (int kt = 0; kt < 8; kt++){
    int idx = ((rbase+la)*256 + kt*32 + g*8) ^ ((la&7)<<3);
    af[kt] = *(const bf16x8*)&inA[idx];
  }
  for (int jt = 0; jt < 8; jt++){
    f32x4 acc = {0.f,0.f,0.f,0.f};
    const float* Wb = W1 + (jt*16+la)*384;
    #pragma unroll
    for (int kt = 0; kt < 8; kt++){
      const float* p = Wb + kt*32 + g*8;
      acc = mfma16(af[kt], cvt8(*(const float4*)p, *(const float4*)(p+4)), acc);
    }
    int j = jt*16 + la;
    #pragma unroll
    for (int rr = 0; rr < 4; rr++){
      int row = rbase + g*4 + rr;
      int R = blk*64 + row;
      AL[R*128 + j] = acc[rr] + b1s[j] + corrs[row]*rs[j];
    }
  }
  for (int jt = 0; jt < 8; jt++){
    f32x4 acc = {0.f,0.f,0.f,0.f};
    const float* Wb = W5 + (jt*16+la)*256;
    #pragma unroll
    for (int kt = 0; kt < 4; kt++){
      const float* p = Wb + kt*32 + g*8;
      acc = mfma16(af[kt], cvt8(*(const float4*)p, *(const float4*)(p+4)), acc);
    }
    int j = jt*16 + la;
    #pragma unroll
    for (int rr = 0; rr < 4; rr++){
      int row = rbase + g*4 + rr;
      int R = blk*64 + row;
      pre5[R*128 + j] = acc[rr] + b5s[j];
    }
  }
}

// ---------------- K2 ----------------
__global__ __launch_bounds__(256) void k2_pre(
    const int* __restrict__ itseq, const float* __restrict__ Eit,
    const float* __restrict__ AL,
    const float* __restrict__ W2, const float* __restrict__ W3,
    const float* __restrict__ W4,
    const float* __restrict__ b2, const float* __restrict__ b3,
    const float* __restrict__ b4,
    float* __restrict__ pre23, float* __restrict__ pre4)
{
  __shared__ __bf16 inA[64*384];
  __shared__ int obase[64];
  __shared__ float b2s[128], b3s[128], b4s[128];
  const int tid = threadIdx.x, blk = blockIdx.x;
  if (tid < 128){ b2s[tid]=b2[tid]; b3s[tid]=b3[tid]; b4s[tid]=b4[tid]; }
  {
    int r = tid >> 2, seg = tid & 3;
    int R = blk*64 + r;
    bool valid = (R < 4064);
    int b_ = R / 127, tau = R % 127;
    if (seg == 0) obase[r] = valid ? (b_*127 + tau) : -1;
    int itv = valid ? itseq[b_*128 + tau] : 0;
    for (int i = 0; i < 96; i++){
      int col = seg*96 + i;
      float v = 0.f;
      if (valid){
        if (col < 128)      v = (tau > 0) ? AL[(b_*128 + tau-1)*128 + col] : 0.f;
        else if (col < 256) v = Eit[itv*128 + (col-128)];
        else                v = AL[(b_*128 + tau)*128 + (col-256)];
      }
      inA[((r*384 + col) ^ ((r&7)<<3))] = (__bf16)v;
    }
  }
  __syncthreads();
  const int w = tid >> 6, lane = tid & 63;
  const int la = lane & 15, g = lane >> 4;
  const int rbase = w*16;
  bf16x8 af[12];
  #pragma unroll
  for (int kt = 0; kt < 12; kt++){
    int idx = ((rbase+la)*384 + kt*32 + g*8) ^ ((la&7)<<3);
    af[kt] = *(const bf16x8*)&inA[idx];
  }
  for (int jt = 0; jt < 16; jt++){
    f32x4 acc = {0.f,0.f,0.f,0.f};
    int j = jt*16 + la;
    const float* Wb = (j < 128) ? (W2 + j*512) : (W3 + (j-128)*512);
    #pragma unroll
    for (int kt = 0; kt < 12; kt++){
      const float* p = Wb + kt*32 + g*8;
      acc = mfma16(af[kt], cvt8(*(const float4*)p, *(const float4*)(p+4)), acc);
    }
    float bias = (j < 128) ? b2s[j] : b3s[j-128];
    #pragma unroll
    for (int rr = 0; rr < 4; rr++){
      int row = rbase + g*4 + rr;
      int ob = obase[row];
      if (ob >= 0) pre23[ob*256 + j] = acc[rr] + bias;
    }
  }
  for (int jt = 0; jt < 8; jt++){
    f32x4 acc = {0.f,0.f,0.f,0.f};
    int j = jt*16 + la;
    const float* Wb = W4 + j*384 + 256;
    #pragma unroll
    for (int kk = 0; kk < 4; kk++){
      const float* p = Wb + kk*32 + g*8;
      acc = mfma16(af[4+kk], cvt8(*(const float4*)p, *(const float4*)(p+4)), acc);
    }
    #pragma unroll
    for (int rr = 0; rr < 4; rr++){
      int row = rbase + g*4 + rr;
      int ob = obase[row];
      if (ob >= 0) pre4[ob*128 + j] = acc[rr] + b4s[j];
    }
  }
}

// ---------------- K3: scan, 32 blocks x 512 threads ----------------
// LDS floats: hB(bf16 2x256x128 = 32768 floats) | htb0 128 | htb1 128 |
//             LGb 128 | zb 128 | qeb0 256 | qeb1 256 | p23L 512 | p4L 256 |
//             qsl(int) 128  => 34688 floats = 138752 B
#define SCAN_LDS_BYTES (34688*4)

__global__ __launch_bounds__(512, 2) void lpkt_scan(
    const float* __restrict__ qmat, const int* __restrict__ qseq,
    const float* __restrict__ h0,
    const float* __restrict__ W2, const float* __restrict__ W3,
    const float* __restrict__ W4,
    const float* __restrict__ pre23, const float* __restrict__ pre4,
    float* __restrict__ hist)
{
  extern __shared__ float lds[];
  __bf16* hB  = (__bf16*)lds;          // 2 buffers x 256x128 (swizzled)
  float* htb0 = lds + 32768;
  float* htb1 = lds + 32896;
  float* LGb  = lds + 33024;
  float* zb   = lds + 33152;
  float* qeb0 = lds + 33280;
  float* qeb1 = lds + 33536;
  float* p23L = lds + 33792;      // [2][256]
  float* p4L  = lds + 34304;      // [2][128]
  int*   qsl  = (int*)(lds + 34560);

  const int tid  = threadIdx.x;
  const int b    = blockIdx.x;
  const int lane = tid & 63;
  const int w    = tid >> 6;           // 8 waves
  const int la   = lane & 15, g = lane >> 4;
  const int jh   = w & 1;              // k-half owned by this wave
  const int cq   = w >> 1;             // column quad (64 columns) of wave pair

  // ---- persistent register weight fragments ----
  bf16x8 af[4][4];                     // W4h rows (jh*4+jj)*16+la
  #pragma unroll
  for (int jj = 0; jj < 4; jj++){
    #pragma unroll
    for (int kt = 0; kt < 4; kt++){
      const float* p = W4 + ((jh*4+jj)*16+la)*384 + kt*32 + g*8;
      af[jj][kt] = cvt8(*(const float4*)p, *(const float4*)(p+4));
    }
  }
  bf16x8 af23[2][4];                   // W2h tile w, W3h tile w
  bf16x8 af4l[4];                      // W4l tile w
  #pragma unroll
  for (int kt = 0; kt < 4; kt++){
    const float* p2 = W2 + (w*16+la)*512 + 384 + kt*32 + g*8;
    const float* p3 = W3 + (w*16+la)*512 + 384 + kt*32 + g*8;
    const float* p4 = W4 + (w*16+la)*384 + 128 + kt*32 + g*8;
    af23[0][kt] = cvt8(*(const float4*)p2, *(const float4*)(p2+4));
    af23[1][kt] = cvt8(*(const float4*)p3, *(const float4*)(p3+4));
    af4l[kt]    = cvt8(*(const float4*)p4, *(const float4*)(p4+4));
  }

  // ---- init staging ----
  if (tid < 128) qsl[tid] = qseq[b*128 + tid];
  __syncthreads();
  const float* pre23b = pre23 + b*127*256;
  const float* pre4b  = pre4  + b*127*128;
  if (tid < 64)       *(float4*)&qeb0[tid*4] = *(const float4*)(qmat + (size_t)qsl[0]*256 + tid*4);
  else if (tid < 128) *(float4*)&qeb1[(tid-64)*4] = *(const float4*)(qmat + (size_t)qsl[1]*256 + (tid-64)*4);
  else if (tid < 192) *(float4*)&p23L[(tid-128)*4] = *(const float4*)(pre23b + (tid-128)*4);
  else if (tid < 224) *(float4*)&p4L[(tid-192)*4]  = *(const float4*)(pre4b  + (tid-192)*4);
  else if (tid < 256){ float4 z4 = {0.f,0.f,0.f,0.f}; *(float4*)&htb0[(tid-224)*4] = z4; }

  // h state -> registers (fp32, D-layout) + bf16 shadow buffer 0
  float4 hreg[4][4];
  #pragma unroll
  for (int cg = 0; cg < 4; cg++){
    const int c_ = cq*64 + cg*16 + la;
    #pragma unroll
    for (int jj = 0; jj < 4; jj++){
      const int k0 = (jh*4+jj)*16 + g*4;
      float4 v = *(const float4*)(h0 + c_*128 + k0);
      hreg[cg][jj] = v;
      bf16x4 hb; hb[0]=(__bf16)v.x; hb[1]=(__bf16)v.y; hb[2]=(__bf16)v.z; hb[3]=(__bf16)v.w;
      *(bf16x4*)&hB[HBIDX(c_, k0)] = hb;
    }
  }
  __syncthreads();
  // htilde0 = sum_c qe0[c] * h0[c][:]
  #pragma unroll
  for (int cg = 0; cg < 4; cg++){
    const int c_ = cq*64 + cg*16 + la;
    float q = qeb0[c_];
    if (q != 0.f){
      #pragma unroll
      for (int jj = 0; jj < 4; jj++){
        const int k0 = (jh*4+jj)*16 + g*4;
        float4 hv = hreg[cg][jj];
        atomicAdd(&htb0[k0+0], q*hv.x);
        atomicAdd(&htb0[k0+1], q*hv.y);
        atomicAdd(&htb0[k0+2], q*hv.z);
        atomicAdd(&htb0[k0+3], q*hv.w);
      }
    }
  }
  __syncthreads();

  for (int tau = 0; tau < 127; tau++){
    float* htc = (tau & 1) ? htb1 : htb0;
    float* htn = (tau & 1) ? htb0 : htb1;
    float* qec = (tau & 1) ? qeb1 : qeb0;
    float* qen = (tau & 1) ? qeb0 : qeb1;
    const float* p23c = p23L + (tau & 1)*256;
    const float* p4c  = p4L  + (tau & 1)*128;
    const __bf16* hBr = hB + (tau & 1)*32768;
    __bf16*       hBw = hB + ((tau+1) & 1)*32768;

    // ---- P0: scalars, zero htn, m23 via MFMA, LG in-register ----
    float qet[4], qnv[4];
    #pragma unroll
    for (int cg = 0; cg < 4; cg++){
      const int c_ = cq*64 + cg*16 + la;
      qet[cg] = qec[c_]; qnv[cg] = qen[c_];
    }
    if (tid < 128) htn[tid] = 0.f;
    {
      bf16x8 xh[4], xl[4];
      #pragma unroll
      for (int kt = 0; kt < 4; kt++){
        int k0 = kt*32 + g*8;
        mk_hilo(*(const float4*)&htc[k0], *(const float4*)&htc[k0+4], xh[kt], xl[kt]);
      }
      f32x4 aL = {0.f,0.f,0.f,0.f}, aG = {0.f,0.f,0.f,0.f};
      #pragma unroll
      for (int kt = 0; kt < 4; kt++){
        aL = mfma16(af23[0][kt], xh[kt], aL);
        aL = mfma16(af23[0][kt], xl[kt], aL);
        aG = mfma16(af23[1][kt], xh[kt], aG);
        aG = mfma16(af23[1][kt], xl[kt], aG);
      }
      float4 lp4 = *(const float4*)&p23c[w*16 + g*4];
      float4 gp4 = *(const float4*)&p23c[128 + w*16 + g*4];
      if (la == 0){
        float4 LG4;
        LG4.x = sigmf(aG[0]+gp4.x) * sigmf(2.f*(aL[0]+lp4.x));
        LG4.y = sigmf(aG[1]+gp4.y) * sigmf(2.f*(aL[1]+lp4.y));
        LG4.z = sigmf(aG[2]+gp4.z) * sigmf(2.f*(aL[2]+lp4.z));
        LG4.w = sigmf(aG[3]+gp4.w) * sigmf(2.f*(aL[3]+lp4.w));
        *(float4*)&LGb[w*16 + g*4] = LG4;
      }
    }
    __syncthreads();                                    // Bb

    // ---- z = W4l @ LG + pre4 ----
    {
      bf16x8 lh[4], ll[4];
      #pragma unroll
      for (int kt = 0; kt < 4; kt++){
        int k0 = kt*32 + g*8;
        mk_hilo(*(const float4*)&LGb[k0], *(const float4*)&LGb[k0+4], lh[kt], ll[kt]);
      }
      f32x4 az = {0.f,0.f,0.f,0.f};
      #pragma unroll
      for (int kt = 0; kt < 4; kt++){
        az = mfma16(af4l[kt], lh[kt], az);
        az = mfma16(af4l[kt], ll[kt], az);
      }
      if (la == 0){
        float4 zp = *(const float4*)&p4c[w*16 + g*4];
        float4 z4 = {az[0]+zp.x, az[1]+zp.y, az[2]+zp.z, az[3]+zp.w};
        *(float4*)&zb[w*16 + g*4] = z4;
      }
    }
    __syncthreads();                                    // B1

    // ---- main: prefetch issue, G^T MFMA + fused register update ----
    float4 pf23, pf4, pfqe;
    const bool dopf = (tau < 126);
    const bool do23 = dopf && (tid < 64);
    const bool do4  = dopf && (tid >= 64) && (tid < 96);
    const bool doqe = dopf && (tid >= 448);
    if (do23) pf23 = *(const float4*)(pre23b + (tau+1)*256 + tid*4);
    if (do4)  pf4  = *(const float4*)(pre4b  + (tau+1)*128 + (tid-64)*4);
    if (doqe) pfqe = *(const float4*)(qmat + (size_t)qsl[tau+2]*256 + (tid-448)*4);

    #pragma unroll
    for (int cg = 0; cg < 4; cg++){
      const int c_ = cq*64 + cg*16 + la;
      bf16x8 bfv[4];
      #pragma unroll
      for (int kt = 0; kt < 4; kt++)
        bfv[kt] = *(const bf16x8*)&hBr[HBIDX(c_, kt*32 + g*8)];
      const float qe_t = qet[cg], qe_n = qnv[cg];
      const bool nz = (qe_n != 0.f);
      #pragma unroll
      for (int jj = 0; jj < 4; jj++){
        f32x4 acc = {0.f,0.f,0.f,0.f};
        #pragma unroll
        for (int kt = 0; kt < 4; kt++)
          acc = mfma16(af[jj][kt], bfv[kt], acc);
        const int k0 = (jh*4+jj)*16 + g*4;
        float4 z4  = *(const float4*)&zb[k0];
        float4 lg4 = *(const float4*)&LGb[k0];
        float4 hp  = hreg[cg][jj];
        float4 hn;
        hn.x = qe_t*lg4.x + sigmf(acc[0] + z4.x)*hp.x;
        hn.y = qe_t*lg4.y + sigmf(acc[1] + z4.y)*hp.y;
        hn.z = qe_t*lg4.z + sigmf(acc[2] + z4.z)*hp.z;
        hn.w = qe_t*lg4.w + sigmf(acc[3] + z4.w)*hp.w;
        hreg[cg][jj] = hn;
        bf16x4 hb; hb[0]=(__bf16)hn.x; hb[1]=(__bf16)hn.y; hb[2]=(__bf16)hn.z; hb[3]=(__bf16)hn.w;
        *(bf16x4*)&hBw[HBIDX(c_, k0)] = hb;
        if (nz){
          atomicAdd(&htn[k0+0], qe_n*hn.x);
          atomicAdd(&htn[k0+1], qe_n*hn.y);
          atomicAdd(&htn[k0+2], qe_n*hn.z);
          atomicAdd(&htn[k0+3], qe_n*hn.w);
        }
      }
    }
    // prefetch writes (consumed only after B2)
    if (do23) *(float4*)&p23L[((tau+1)&1)*256 + tid*4] = pf23;
    if (do4)  *(float4*)&p4L[((tau+1)&1)*128 + (tid-64)*4] = pf4;
    if (doqe) *(float4*)&qec[(tid-448)*4] = pfqe;       // qe[tau+2]
    __syncthreads();                                    // B2

    // stream h_tilde[tau+1] to workspace (off critical path)
    if (tid < 32){
      float4 v = *(const float4*)&htn[tid*4];
      *(float4*)(hist + ((size_t)b*127 + tau)*128 + tid*4) = v;
    }
  }
}

// ---------------- K4: batched y ----------------
__global__ __launch_bounds__(128) void k4_y(
    const float* __restrict__ hist, const float* __restrict__ pre5,
    const float* __restrict__ W5, float* __restrict__ out)
{
  const int R = blockIdx.x;            // 0..4095 = b*128+s
  const int s = R & 127, b = R >> 7;
  const int j = threadIdx.x;
  __shared__ float xs[128];
  __shared__ float partial[2];
  if (s == 0){ if (j == 0) out[R] = 0.f; return; }
  xs[j] = hist[((size_t)b*127 + (s-1))*128 + j];
  __syncthreads();
  const float* wr = W5 + j*256 + 128;
  float acc = pre5[(size_t)R*128 + j];
  #pragma unroll
  for (int k = 0; k < 128; k += 4){
    float4 wv = *(const float4*)&wr[k];
    float4 xv = *(const float4*)&xs[k];
    acc += wv.x*xv.x + wv.y*xv.y + wv.z*xv.z + wv.w*xv.w;
  }
  float v = sigmf(acc);
  #pragma unroll
  for (int m = 1; m < 64; m <<= 1) v += __shfl_xor(v, m);
  if ((j & 63) == 0) partial[j >> 6] = v;
  __syncthreads();
  if (j == 0) out[R] = (partial[0] + partial[1]) * (1.f/128.f);
}

// ---------------- host launch ----------------
extern "C" void kernel_launch(void* const* d_in, const int* in_sizes, int n_in,
                              void* d_out, int out_size, void* d_ws, size_t ws_size,
                              hipStream_t stream) {
  const int*   qseq  = (const int*)  d_in[0];
  const int*   itseq = (const int*)  d_in[1];
  const int*   utseq = (const int*)  d_in[2];
  const float* corr  = (const float*)d_in[3];
  const float* Eq    = (const float*)d_in[4];
  const float* Eit   = (const float*)d_in[5];
  const float* Eut   = (const float*)d_in[6];
  const float* qmat  = (const float*)d_in[7];
  const float* h0    = (const float*)d_in[8];
  const float* W1    = (const float*)d_in[9];
  const float* b1    = (const float*)d_in[10];
  const float* W2    = (const float*)d_in[11];
  const float* b2    = (const float*)d_in[12];
  const float* W3    = (const float*)d_in[13];
  const float* b3    = (const float*)d_in[14];
  const float* W4    = (const float*)d_in[15];
  const float* b4    = (const float*)d_in[16];
  const float* W5    = (const float*)d_in[17];
  const float* b5    = (const float*)d_in[18];
  float* out = (float*)d_out;

  float* ws    = (float*)d_ws;
  float* AL    = ws;                    // 4096*128 ; reused as hist after k2
  float* hist  = ws;                    // 32*127*128 <= AL size
  float* pre5  = ws + 524288;           // 4096*128
  float* pre23 = ws + 1048576;          // 4064*256
  float* pre4  = ws + 2088960;          // 4064*128
  float* rs1c  = ws + 2609152;          // 128

  (void)hipFuncSetAttribute(reinterpret_cast<const void*>(&lpkt_scan),
                            hipFuncAttributeMaxDynamicSharedMemorySize,
                            SCAN_LDS_BYTES);

  hipLaunchKernelGGL(k0_rs1c, dim3(1), dim3(128), 0, stream, W1, rs1c);
  hipLaunchKernelGGL(k1_al, dim3(64), dim3(256), 0, stream,
                     qseq, utseq, corr, Eq, Eut, W1, b1, W5, b5, rs1c, AL, pre5);
  hipLaunchKernelGGL(k2_pre, dim3(64), dim3(256), 0, stream,
                     itseq, Eit, AL, W2, W3, W4, b2, b3, b4, pre23, pre4);
  hipLaunchKernelGGL(lpkt_scan, dim3(32), dim3(512), SCAN_LDS_BYTES, stream,
                     qmat, qseq, h0, W2, W3, W4, pre23, pre4, hist);
  hipLaunchKernelGGL(k4_y, dim3(4096), dim3(128), 0, stream,
                     hist, pre5, W5, out);
}

// Round 4
// 903.700 us; speedup vs baseline: 2.8337x; 1.1757x over previous
//
#include <hip/hip_runtime.h>
#include <hip/hip_bf16.h>

// LPKT+ forward. B=32, S=128, C=256, K=128, DC=128, T=127 scan steps.
//
//  K1: AL = [eq|eut]@W1a^T + b1 + correct*rs1c ; pre5 = eq@W5q^T + b5
//      (rs1c = row-sums of W1 c-block, computed in-block)
//  K2: pre23 = [AL[t-1]|it|AL[t]] @ [W2a|W3a]^T + b ; pre4 = it@W4i^T + b4
//  K3 (scan): 32 blocks x 512 threads (8 waves).
//      h fp32 in registers (D-layout, 64 VGPR) + bf16 shadow in LDS (dbuf,
//      swizzled) as MFMA B-operand. W4h split 4-ways over j (af 32 regs/wave);
//      wave = (jq = w&3 j-quarter, ch = w>>2 column-half). 3 barriers/step.
//  K4: batched y = mean_j sigmoid(pre5 + W5h @ ht_hist).

typedef __bf16 bf16x8 __attribute__((ext_vector_type(8)));
typedef __bf16 bf16x4 __attribute__((ext_vector_type(4)));
typedef float f32x4 __attribute__((ext_vector_type(4)));

// bf16 shadow-h element index; XOR swizzle keeps b128 reads and b64 writes
// bank-spread (validated rounds 2-3).
#define HBIDX(c,k) ((((c)<<7)) + ((k) ^ (((c)&15)<<3)))

__device__ __forceinline__ float sigmf(float x){
  return __builtin_amdgcn_rcpf(1.0f + __expf(-x));
}

__device__ __forceinline__ bf16x8 cvt8(float4 a, float4 b){
  bf16x8 r;
  r[0]=(__bf16)a.x; r[1]=(__bf16)a.y; r[2]=(__bf16)a.z; r[3]=(__bf16)a.w;
  r[4]=(__bf16)b.x; r[5]=(__bf16)b.y; r[6]=(__bf16)b.z; r[7]=(__bf16)b.w;
  return r;
}

// hi/lo bf16 split of 8 fp32 values (fp32-grade MFMA input)
__device__ __forceinline__ void mk_hilo(float4 a, float4 b, bf16x8& hi, bf16x8& lo){
  float v[8] = {a.x,a.y,a.z,a.w,b.x,b.y,b.z,b.w};
  #pragma unroll
  for (int i = 0; i < 8; i++){
    __bf16 h = (__bf16)v[i];
    hi[i] = h;
    lo[i] = (__bf16)(v[i] - (float)h);
  }
}

__device__ __forceinline__ f32x4 mfma16(bf16x8 a, bf16x8 b, f32x4 c){
  return __builtin_amdgcn_mfma_f32_16x16x32_bf16(a, b, c, 0, 0, 0);
}

// ---------------- K1 ----------------
__global__ __launch_bounds__(256) void k1_al(
    const int* __restrict__ qseq, const int* __restrict__ utseq,
    const float* __restrict__ corr,
    const float* __restrict__ Eq, const float* __restrict__ Eut,
    const float* __restrict__ W1, const float* __restrict__ b1,
    const float* __restrict__ W5, const float* __restrict__ b5,
    float* __restrict__ AL, float* __restrict__ pre5)
{
  __shared__ __bf16 inA[64*256];
  __shared__ float corrs[64];
  __shared__ float b1s[128], b5s[128], rsp[256];
  const int tid = threadIdx.x, blk = blockIdx.x;
  if (tid < 128){ b1s[tid]=b1[tid]; b5s[tid]=b5[tid]; }
  { // rs1c partial sums (fold of old k0)
    int j = tid & 127, hf = tid >> 7;
    const float* p = W1 + j*384 + 256 + hf*64;
    float s = 0.f;
    for (int i = 0; i < 64; i++) s += p[i];
    rsp[tid] = s;
  }
  {
    int r = tid >> 2, seg = tid & 3;
    int R = blk*64 + r;
    int qi = qseq[R], ui = utseq[R];
    if (seg == 0) corrs[r] = corr[R];
    for (int i = 0; i < 64; i++){
      int col = seg*64 + i;
      float v = (col < 128) ? Eq[qi*128 + col] : Eut[ui*128 + (col-128)];
      inA[((r*256 + col) ^ ((r&7)<<3))] = (__bf16)v;
    }
  }
  __syncthreads();
  const int w = tid >> 6, lane = tid & 63;
  const int la = lane & 15, g = lane >> 4;
  const int rbase = w*16;
  bf16x8 af[8];
  #pragma unroll
  for (int kt = 0; kt < 8; kt++){
    int idx = ((rbase+la)*256 + kt*32 + g*8) ^ ((la&7)<<3);
    af[kt] = *(const bf16x8*)&inA[idx];
  }
  for (int jt = 0; jt < 8; jt++){
    f32x4 acc = {0.f,0.f,0.f,0.f};
    const float* Wb = W1 + (jt*16+la)*384;
    #pragma unroll
    for (int kt = 0; kt < 8; kt++){
      const float* p = Wb + kt*32 + g*8;
      acc = mfma16(af[kt], cvt8(*(const float4*)p, *(const float4*)(p+4)), acc);
    }
    int j = jt*16 + la;
    float rsj = rsp[j] + rsp[j+128];
    #pragma unroll
    for (int rr = 0; rr < 4; rr++){
      int row = rbase + g*4 + rr;
      int R = blk*64 + row;
      AL[R*128 + j] = acc[rr] + b1s[j] + corrs[row]*rsj;
    }
  }
  for (int jt = 0; jt < 8; jt++){
    f32x4 acc = {0.f,0.f,0.f,0.f};
    const float* Wb = W5 + (jt*16+la)*256;
    #pragma unroll
    for (int kt = 0; kt < 4; kt++){
      const float* p = Wb + kt*32 + g*8;
      acc = mfma16(af[kt], cvt8(*(const float4*)p, *(const float4*)(p+4)), acc);
    }
    int j = jt*16 + la;
    #pragma unroll
    for (int rr = 0; rr < 4; rr++){
      int row = rbase + g*4 + rr;
      int R = blk*64 + row;
      pre5[R*128 + j] = acc[rr] + b5s[j];
    }
  }
}

// ---------------- K2 ----------------
__global__ __launch_bounds__(256) void k2_pre(
    const int* __restrict__ itseq, const float* __restrict__ Eit,
    const float* __restrict__ AL,
    const float* __restrict__ W2, const float* __restrict__ W3,
    const float* __restrict__ W4,
    const float* __restrict__ b2, const float* __restrict__ b3,
    const float* __restrict__ b4,
    float* __restrict__ pre23, float* __restrict__ pre4)
{
  __shared__ __bf16 inA[64*384];
  __shared__ int obase[64];
  __shared__ float b2s[128], b3s[128], b4s[128];
  const int tid = threadIdx.x, blk = blockIdx.x;
  if (tid < 128){ b2s[tid]=b2[tid]; b3s[tid]=b3[tid]; b4s[tid]=b4[tid]; }
  {
    int r = tid >> 2, seg = tid & 3;
    int R = blk*64 + r;
    bool valid = (R < 4064);
    int b_ = R / 127, tau = R % 127;
    if (seg == 0) obase[r] = valid ? (b_*127 + tau) : -1;
    int itv = valid ? itseq[b_*128 + tau] : 0;
    for (int i = 0; i < 96; i++){
      int col = seg*96 + i;
      float v = 0.f;
      if (valid){
        if (col < 128)      v = (tau > 0) ? AL[(b_*128 + tau-1)*128 + col] : 0.f;
        else if (col < 256) v = Eit[itv*128 + (col-128)];
        else                v = AL[(b_*128 + tau)*128 + (col-256)];
      }
      inA[((r*384 + col) ^ ((r&7)<<3))] = (__bf16)v;
    }
  }
  __syncthreads();
  const int w = tid >> 6, lane = tid & 63;
  const int la = lane & 15, g = lane >> 4;
  const int rbase = w*16;
  bf16x8 af[12];
  #pragma unroll
  for (int kt = 0; kt < 12; kt++){
    int idx = ((rbase+la)*384 + kt*32 + g*8) ^ ((la&7)<<3);
    af[kt] = *(const bf16x8*)&inA[idx];
  }
  for (int jt = 0; jt < 16; jt++){
    f32x4 acc = {0.f,0.f,0.f,0.f};
    int j = jt*16 + la;
    const float* Wb = (j < 128) ? (W2 + j*512) : (W3 + (j-128)*512);
    #pragma unroll
    for (int kt = 0; kt < 12; kt++){
      const float* p = Wb + kt*32 + g*8;
      acc = mfma16(af[kt], cvt8(*(const float4*)p, *(const float4*)(p+4)), acc);
    }
    float bias = (j < 128) ? b2s[j] : b3s[j-128];
    #pragma unroll
    for (int rr = 0; rr < 4; rr++){
      int row = rbase + g*4 + rr;
      int ob = obase[row];
      if (ob >= 0) pre23[ob*256 + j] = acc[rr] + bias;
    }
  }
  for (int jt = 0; jt < 8; jt++){
    f32x4 acc = {0.f,0.f,0.f,0.f};
    int j = jt*16 + la;
    const float* Wb = W4 + j*384 + 256;
    #pragma unroll
    for (int kk = 0; kk < 4; kk++){
      const float* p = Wb + kk*32 + g*8;
      acc = mfma16(af[4+kk], cvt8(*(const float4*)p, *(const float4*)(p+4)), acc);
    }
    #pragma unroll
    for (int rr = 0; rr < 4; rr++){
      int row = rbase + g*4 + rr;
      int ob = obase[row];
      if (ob >= 0) pre4[ob*128 + j] = acc[rr] + b4s[j];
    }
  }
}

// ---------------- K3: scan, 32 blocks x 512 threads ----------------
// LDS floats: hB(bf16 2x256x128 = 32768 f) | htb0 128 | htb1 128 | LGb 128 |
//             zb 128 | qeb[3][256] 768 | p23L[2][256] 512 | p4L[2][128] 256 |
//             qsl(int) 128  => 34944 floats = 139776 B
#define SCAN_LDS_BYTES (34944*4)

__global__ __launch_bounds__(512, 2) void lpkt_scan(
    const float* __restrict__ qmat, const int* __restrict__ qseq,
    const float* __restrict__ h0,
    const float* __restrict__ W2, const float* __restrict__ W3,
    const float* __restrict__ W4,
    const float* __restrict__ pre23, const float* __restrict__ pre4,
    float* __restrict__ hist)
{
  extern __shared__ float lds[];
  __bf16* hB  = (__bf16*)lds;          // 2 buffers x 256x128 (swizzled)
  float* htb0 = lds + 32768;
  float* htb1 = lds + 32896;
  float* LGb  = lds + 33024;
  float* zb   = lds + 33152;
  float* qeb  = lds + 33280;      // [3][256]
  float* p23L = lds + 34048;      // [2][256]
  float* p4L  = lds + 34560;      // [2][128]
  int*   qsl  = (int*)(lds + 34816);

  const int tid  = threadIdx.x;
  const int b    = blockIdx.x;
  const int lane = tid & 63;
  const int w    = tid >> 6;           // 8 waves
  const int la   = lane & 15, g = lane >> 4;
  const int jq   = w & 3;              // j-quarter of W4h rows / k-quarter of h
  const int ch   = w >> 2;             // column half (128 columns)

  // ---- persistent register weight fragments ----
  bf16x8 af[2][4];                     // W4h rows (jq*2+jj)*16+la  (32 regs)
  #pragma unroll
  for (int jj = 0; jj < 2; jj++){
    #pragma unroll
    for (int kt = 0; kt < 4; kt++){
      const float* p = W4 + ((jq*2+jj)*16+la)*384 + kt*32 + g*8;
      af[jj][kt] = cvt8(*(const float4*)p, *(const float4*)(p+4));
    }
  }
  bf16x8 af23[2][4];                   // W2h tile w, W3h tile w (32 regs)
  bf16x8 af4l[4];                      // W4l tile w (16 regs)
  #pragma unroll
  for (int kt = 0; kt < 4; kt++){
    const float* p2 = W2 + (w*16+la)*512 + 384 + kt*32 + g*8;
    const float* p3 = W3 + (w*16+la)*512 + 384 + kt*32 + g*8;
    const float* p4 = W4 + (w*16+la)*384 + 128 + kt*32 + g*8;
    af23[0][kt] = cvt8(*(const float4*)p2, *(const float4*)(p2+4));
    af23[1][kt] = cvt8(*(const float4*)p3, *(const float4*)(p3+4));
    af4l[kt]    = cvt8(*(const float4*)p4, *(const float4*)(p4+4));
  }

  // ---- init staging ----
  if (tid < 128) qsl[tid] = qseq[b*128 + tid];
  __syncthreads();
  const float* pre23b = pre23 + b*127*256;
  const float* pre4b  = pre4  + b*127*128;
  if (tid < 64)       *(float4*)&qeb[tid*4] = *(const float4*)(qmat + (size_t)qsl[0]*256 + tid*4);
  else if (tid < 128) *(float4*)&qeb[256 + (tid-64)*4] = *(const float4*)(qmat + (size_t)qsl[1]*256 + (tid-64)*4);
  else if (tid < 192) *(float4*)&p23L[(tid-128)*4] = *(const float4*)(pre23b + (tid-128)*4);
  else if (tid < 224) *(float4*)&p4L[(tid-192)*4]  = *(const float4*)(pre4b  + (tid-192)*4);
  else if (tid < 256){ float4 z4i = {0.f,0.f,0.f,0.f}; *(float4*)&htb0[(tid-224)*4] = z4i; }

  // h state -> registers (fp32, D-layout) + bf16 shadow buffer 0
  float4 hreg[8][2];
  #pragma unroll
  for (int cg = 0; cg < 8; cg++){
    const int c_ = ch*128 + cg*16 + la;
    #pragma unroll
    for (int jj = 0; jj < 2; jj++){
      const int k0 = (jq*2+jj)*16 + g*4;
      float4 v = *(const float4*)(h0 + c_*128 + k0);
      hreg[cg][jj] = v;
      bf16x4 hb; hb[0]=(__bf16)v.x; hb[1]=(__bf16)v.y; hb[2]=(__bf16)v.z; hb[3]=(__bf16)v.w;
      *(bf16x4*)&hB[HBIDX(c_, k0)] = hb;
    }
  }
  __syncthreads();
  // htilde0 = sum_c qe0[c] * h0[c][:]
  #pragma unroll
  for (int cg = 0; cg < 8; cg++){
    const int c_ = ch*128 + cg*16 + la;
    float q = qeb[c_];
    if (q != 0.f){
      #pragma unroll
      for (int jj = 0; jj < 2; jj++){
        const int k0 = (jq*2+jj)*16 + g*4;
        float4 hv = hreg[cg][jj];
        atomicAdd(&htb0[k0+0], q*hv.x);
        atomicAdd(&htb0[k0+1], q*hv.y);
        atomicAdd(&htb0[k0+2], q*hv.z);
        atomicAdd(&htb0[k0+3], q*hv.w);
      }
    }
  }
  __syncthreads();

  int i0 = 0, i1 = 1, i2 = 2;          // qe triple-buffer rotation

  for (int tau = 0; tau < 127; tau++){
    float* htc = (tau & 1) ? htb1 : htb0;
    float* htn = (tau & 1) ? htb0 : htb1;
    float* qec = qeb + i0*256;
    float* qen = qeb + i1*256;
    float* qep = qeb + i2*256;
    const float* p23c = p23L + (tau & 1)*256;
    const float* p4c  = p4L  + (tau & 1)*128;
    const __bf16* hBr = hB + (tau & 1)*32768;
    __bf16*       hBw = hB + ((tau+1) & 1)*32768;

    // ---- P0: zero htn, m23 via MFMA (split chains), LG in-register ----
    if (tid < 128) htn[tid] = 0.f;
    {
      bf16x8 xh[4], xl[4];
      #pragma unroll
      for (int kt = 0; kt < 4; kt++){
        int k0 = kt*32 + g*8;
        mk_hilo(*(const float4*)&htc[k0], *(const float4*)&htc[k0+4], xh[kt], xl[kt]);
      }
      f32x4 aLh = {0.f,0.f,0.f,0.f}, aLl = {0.f,0.f,0.f,0.f};
      f32x4 aGh = {0.f,0.f,0.f,0.f}, aGl = {0.f,0.f,0.f,0.f};
      #pragma unroll
      for (int kt = 0; kt < 4; kt++){
        aLh = mfma16(af23[0][kt], xh[kt], aLh);
        aLl = mfma16(af23[0][kt], xl[kt], aLl);
        aGh = mfma16(af23[1][kt], xh[kt], aGh);
        aGl = mfma16(af23[1][kt], xl[kt], aGl);
      }
      if (la == 0){
        float4 lp4 = *(const float4*)&p23c[w*16 + g*4];
        float4 gp4 = *(const float4*)&p23c[128 + w*16 + g*4];
        float4 LG4;
        LG4.x = sigmf(aGh[0]+aGl[0]+gp4.x) * sigmf(2.f*(aLh[0]+aLl[0]+lp4.x));
        LG4.y = sigmf(aGh[1]+aGl[1]+gp4.y) * sigmf(2.f*(aLh[1]+aLl[1]+lp4.y));
        LG4.z = sigmf(aGh[2]+aGl[2]+gp4.z) * sigmf(2.f*(aLh[2]+aLl[2]+lp4.z));
        LG4.w = sigmf(aGh[3]+aGl[3]+gp4.w) * sigmf(2.f*(aLh[3]+aLl[3]+lp4.w));
        *(float4*)&LGb[w*16 + g*4] = LG4;
      }
    }
    __syncthreads();                                    // Bb

    // ---- z = W4l @ LG + pre4 (LG hi-only; LG in (0,1), err ~2e-4) ----
    {
      bf16x8 lh[4];
      #pragma unroll
      for (int kt = 0; kt < 4; kt++){
        int k0 = kt*32 + g*8;
        lh[kt] = cvt8(*(const float4*)&LGb[k0], *(const float4*)&LGb[k0+4]);
      }
      f32x4 az0 = {0.f,0.f,0.f,0.f}, az1 = {0.f,0.f,0.f,0.f};
      az0 = mfma16(af4l[0], lh[0], az0);
      az1 = mfma16(af4l[1], lh[1], az1);
      az0 = mfma16(af4l[2], lh[2], az0);
      az1 = mfma16(af4l[3], lh[3], az1);
      if (la == 0){
        float4 zp = *(const float4*)&p4c[w*16 + g*4];
        float4 zv = {az0[0]+az1[0]+zp.x, az0[1]+az1[1]+zp.y,
                     az0[2]+az1[2]+zp.z, az0[3]+az1[3]+zp.w};
        *(float4*)&zb[w*16 + g*4] = zv;
      }
    }
    __syncthreads();                                    // B1

    // ---- main: prefetch issue, hoisted z/LG, G MFMA + fused reg update ----
    float4 pf23, pf4, pfqe;
    const bool dopf = (tau < 126);
    const bool do23 = dopf && (tid < 64);
    const bool do4  = dopf && (tid >= 64) && (tid < 96);
    const bool doqe = dopf && (tid >= 448);
    if (do23) pf23 = *(const float4*)(pre23b + (tau+1)*256 + tid*4);
    if (do4)  pf4  = *(const float4*)(pre4b  + (tau+1)*128 + (tid-64)*4);
    if (doqe) pfqe = *(const float4*)(qmat + (size_t)qsl[tau+2]*256 + (tid-448)*4);

    float4 z4[2], lg4[2];
    #pragma unroll
    for (int jj = 0; jj < 2; jj++){
      const int k0 = (jq*2+jj)*16 + g*4;
      z4[jj]  = *(const float4*)&zb[k0];
      lg4[jj] = *(const float4*)&LGb[k0];
    }

    #pragma unroll
    for (int cg = 0; cg < 8; cg++){
      const int c_ = ch*128 + cg*16 + la;
      bf16x8 bfv[4];
      #pragma unroll
      for (int kt = 0; kt < 4; kt++)
        bfv[kt] = *(const bf16x8*)&hBr[HBIDX(c_, kt*32 + g*8)];
      const float qe_t = qec[c_], qe_n = qen[c_];
      const bool nz = (qe_n != 0.f);
      #pragma unroll
      for (int jj = 0; jj < 2; jj++){
        f32x4 acc = {0.f,0.f,0.f,0.f};
        #pragma unroll
        for (int kt = 0; kt < 4; kt++)
          acc = mfma16(af[jj][kt], bfv[kt], acc);
        const int k0 = (jq*2+jj)*16 + g*4;
        float4 hp = hreg[cg][jj];
        float4 hn;
        hn.x = qe_t*lg4[jj].x + sigmf(acc[0] + z4[jj].x)*hp.x;
        hn.y = qe_t*lg4[jj].y + sigmf(acc[1] + z4[jj].y)*hp.y;
        hn.z = qe_t*lg4[jj].z + sigmf(acc[2] + z4[jj].z)*hp.z;
        hn.w = qe_t*lg4[jj].w + sigmf(acc[3] + z4[jj].w)*hp.w;
        hreg[cg][jj] = hn;
        bf16x4 hb; hb[0]=(__bf16)hn.x; hb[1]=(__bf16)hn.y; hb[2]=(__bf16)hn.z; hb[3]=(__bf16)hn.w;
        *(bf16x4*)&hBw[HBIDX(c_, k0)] = hb;
        if (nz){
          atomicAdd(&htn[k0+0], qe_n*hn.x);
          atomicAdd(&htn[k0+1], qe_n*hn.y);
          atomicAdd(&htn[k0+2], qe_n*hn.z);
          atomicAdd(&htn[k0+3], qe_n*hn.w);
        }
      }
    }
    // prefetch writes (consumed only after B2)
    if (do23) *(float4*)&p23L[((tau+1)&1)*256 + tid*4] = pf23;
    if (do4)  *(float4*)&p4L[((tau+1)&1)*128 + (tid-64)*4] = pf4;
    if (doqe) *(float4*)&qep[(tid-448)*4] = pfqe;       // qe[tau+2] -> third buffer
    __syncthreads();                                    // B2

    // stream h_tilde[tau+1] to workspace (off critical path)
    if (tid < 32){
      float4 v = *(const float4*)&htn[tid*4];
      *(float4*)(hist + ((size_t)b*127 + tau)*128 + tid*4) = v;
    }
    int t_ = i0; i0 = i1; i1 = i2; i2 = t_;
  }
}

// ---------------- K4: batched y ----------------
__global__ __launch_bounds__(128) void k4_y(
    const float* __restrict__ hist, const float* __restrict__ pre5,
    const float* __restrict__ W5, float* __restrict__ out)
{
  const int R = blockIdx.x;            // 0..4095 = b*128+s
  const int s = R & 127, b = R >> 7;
  const int j = threadIdx.x;
  __shared__ float xs[128];
  __shared__ float partial[2];
  if (s == 0){ if (j == 0) out[R] = 0.f; return; }
  xs[j] = hist[((size_t)b*127 + (s-1))*128 + j];
  __syncthreads();
  const float* wr = W5 + j*256 + 128;
  float acc = pre5[(size_t)R*128 + j];
  #pragma unroll
  for (int k = 0; k < 128; k += 4){
    float4 wv = *(const float4*)&wr[k];
    float4 xv = *(const float4*)&xs[k];
    acc += wv.x*xv.x + wv.y*xv.y + wv.z*xv.z + wv.w*xv.w;
  }
  float v = sigmf(acc);
  #pragma unroll
  for (int m = 1; m < 64; m <<= 1) v += __shfl_xor(v, m);
  if ((j & 63) == 0) partial[j >> 6] = v;
  __syncthreads();
  if (j == 0) out[R] = (partial[0] + partial[1]) * (1.f/128.f);
}

// ---------------- host launch ----------------
extern "C" void kernel_launch(void* const* d_in, const int* in_sizes, int n_in,
                              void* d_out, int out_size, void* d_ws, size_t ws_size,
                              hipStream_t stream) {
  const int*   qseq  = (const int*)  d_in[0];
  const int*   itseq = (const int*)  d_in[1];
  const int*   utseq = (const int*)  d_in[2];
  const float* corr  = (const float*)d_in[3];
  const float* Eq    = (const float*)d_in[4];
  const float* Eit   = (const float*)d_in[5];
  const float* Eut   = (const float*)d_in[6];
  const float* qmat  = (const float*)d_in[7];
  const float* h0    = (const float*)d_in[8];
  const float* W1    = (const float*)d_in[9];
  const float* b1    = (const float*)d_in[10];
  const float* W2    = (const float*)d_in[11];
  const float* b2    = (const float*)d_in[12];
  const float* W3    = (const float*)d_in[13];
  const float* b3    = (const float*)d_in[14];
  const float* W4    = (const float*)d_in[15];
  const float* b4    = (const float*)d_in[16];
  const float* W5    = (const float*)d_in[17];
  const float* b5    = (const float*)d_in[18];
  float* out = (float*)d_out;

  float* ws    = (float*)d_ws;
  float* AL    = ws;                    // 4096*128 ; reused as hist after k2
  float* hist  = ws;                    // 32*127*128 <= AL size
  float* pre5  = ws + 524288;           // 4096*128
  float* pre23 = ws + 1048576;          // 4064*256
  float* pre4  = ws + 2088960;          // 4064*128

  (void)hipFuncSetAttribute(reinterpret_cast<const void*>(&lpkt_scan),
                            hipFuncAttributeMaxDynamicSharedMemorySize,
                            SCAN_LDS_BYTES);

  hipLaunchKernelGGL(k1_al, dim3(64), dim3(256), 0, stream,
                     qseq, utseq, corr, Eq, Eut, W1, b1, W5, b5, AL, pre5);
  hipLaunchKernelGGL(k2_pre, dim3(64), dim3(256), 0, stream,
                     itseq, Eit, AL, W2, W3, W4, b2, b3, b4, pre23, pre4);
  hipLaunchKernelGGL(lpkt_scan, dim3(32), dim3(512), SCAN_LDS_BYTES, stream,
                     qmat, qseq, h0, W2, W3, W4, pre23, pre4, hist);
  hipLaunchKernelGGL(k4_y, dim3(4096), dim3(128), 0, stream,
                     hist, pre5, W5, out);
}